// Round 1
// baseline (1283.404 us; speedup 1.0000x reference)
//
#include <hip/hip_runtime.h>
#include <hip/hip_bf16.h>

#define VOCAB 32000
#define EMB 64
#define BATCH 4
#define SEQ 2048
#define CHUNK 128
#define NCHUNK (SEQ / CHUNK)   // 16
#define M_TOTAL (BATCH * SEQ)  // 8192
#define NCH 25                 // N chunks for GEMM grid
#define NCOLS (VOCAB / NCH)    // 1280 cols per chunk

typedef __bf16 bf16x8 __attribute__((ext_vector_type(8)));
typedef float f32x4 __attribute__((ext_vector_type(4)));

// ---- Pass 1: per-chunk partial sums of gathered embeddings ----
// grid (BATCH, NCHUNK), block 64 (thread = emb dim)
__global__ void k_partial(const float* __restrict__ emb, const int* __restrict__ x,
                          float* __restrict__ partial) {
    int b = blockIdx.x, c = blockIdx.y, e = threadIdx.x;
    const int base = b * SEQ + c * CHUNK;
    float s = 0.f;
#pragma unroll 4
    for (int p = 0; p < CHUNK; ++p) {
        int row = x[base + p];
        s += emb[row * EMB + e];
    }
    partial[(b * NCHUNK + c) * EMB + e] = s;
}

// ---- Pass 2: running prefix mean within chunk, write bf16 A ----
// grid (BATCH, NCHUNK), block 64
__global__ void k_prefix(const float* __restrict__ emb, const int* __restrict__ x,
                         const float* __restrict__ partial,
                         __hip_bfloat16* __restrict__ A) {
    int b = blockIdx.x, c = blockIdx.y, e = threadIdx.x;
    float s = 0.f;
    for (int j = 0; j < c; ++j) s += partial[(b * NCHUNK + j) * EMB + e];
    const int base = b * SEQ + c * CHUNK;
#pragma unroll 4
    for (int p = 0; p < CHUNK; ++p) {
        int row = x[base + p];
        s += emb[row * EMB + e];
        int pos = c * CHUNK + p;               // position within sequence
        float mean = s / (float)(pos + 1);
        A[(base + p) * EMB + e] = __float2bfloat16(mean);
    }
}

// ---- W fp32 -> bf16 (keeps N x K row-major = B^T layout) ----
__global__ void k_conv(const float* __restrict__ W, __hip_bfloat16* __restrict__ Wb, int n) {
    int i = blockIdx.x * blockDim.x + threadIdx.x;
    int stride = gridDim.x * blockDim.x;
    for (; i < n; i += stride) Wb[i] = __float2bfloat16(W[i]);
}

// ---- GEMM: C(8192 x 32000) = A(8192x64,bf16) * Wb^T + bias, fp32 out ----
// block = 256 threads = 4 waves; wave handles one 16-row M tile,
// loops over NCOLS columns of its N chunk in 16-col tiles.
// 16x16x32 bf16 MFMA, verified layouts:
//   A:   a[j] = A[m = lane&15][k = (lane>>4)*8 + j]
//   B:   b[j] = B[k = (lane>>4)*8 + j][n = lane&15]   (Wb is N x K row-major)
//   C/D: col = lane&15, row = (lane>>4)*4 + reg
__global__ __launch_bounds__(256) void k_gemm(const __hip_bfloat16* __restrict__ A,
                                              const __hip_bfloat16* __restrict__ Wb,
                                              const float* __restrict__ bias,
                                              float* __restrict__ C) {
    const int wave = threadIdx.x >> 6;
    const int lane = threadIdx.x & 63;
    const int quad = lane >> 4;
    const int lo16 = lane & 15;

    const int mtile = blockIdx.x * 4 + wave;   // 0..511
    const int m_base = mtile * 16;
    const int n_base0 = blockIdx.y * NCOLS;

    // A fragments for full K=64, held in registers for the whole N loop
    const int m = m_base + lo16;
    bf16x8 a0 = *reinterpret_cast<const bf16x8*>(A + m * EMB + quad * 8);
    bf16x8 a1 = *reinterpret_cast<const bf16x8*>(A + m * EMB + 32 + quad * 8);

    for (int nt = 0; nt < NCOLS; nt += 16) {
        const int n = n_base0 + nt + lo16;
        bf16x8 b0 = *reinterpret_cast<const bf16x8*>(Wb + n * EMB + quad * 8);
        bf16x8 b1 = *reinterpret_cast<const bf16x8*>(Wb + n * EMB + 32 + quad * 8);
        float bv = bias[n];
        f32x4 acc = {bv, bv, bv, bv};
        acc = __builtin_amdgcn_mfma_f32_16x16x32_bf16(a0, b0, acc, 0, 0, 0);
        acc = __builtin_amdgcn_mfma_f32_16x16x32_bf16(a1, b1, acc, 0, 0, 0);

        float* cp = C + (size_t)(m_base + quad * 4) * VOCAB + n;
        cp[0 * VOCAB] = acc[0];
        cp[1 * VOCAB] = acc[1];
        cp[2 * VOCAB] = acc[2];
        cp[3 * VOCAB] = acc[3];
    }
}

extern "C" void kernel_launch(void* const* d_in, const int* in_sizes, int n_in,
                              void* d_out, int out_size, void* d_ws, size_t ws_size,
                              hipStream_t stream) {
    const float* emb  = (const float*)d_in[0];  // (32000, 64)
    const float* W    = (const float*)d_in[1];  // (32000, 64)
    const float* bias = (const float*)d_in[2];  // (32000,)
    const int*   x    = (const int*)d_in[3];    // (4, 2048)
    float* C = (float*)d_out;                   // (4, 2048, 32000)

    // workspace layout
    char* ws = (char*)d_ws;
    __hip_bfloat16* A  = (__hip_bfloat16*)ws;                       // 8192*64*2 = 1,048,576 B
    __hip_bfloat16* Wb = (__hip_bfloat16*)(ws + 1048576);           // 32000*64*2 = 4,096,000 B
    float* partial     = (float*)(ws + 1048576 + 4096000);          // 4*16*64*4 = 16,384 B

    k_partial<<<dim3(BATCH, NCHUNK), 64, 0, stream>>>(emb, x, partial);
    k_conv<<<2048, 256, 0, stream>>>(W, Wb, VOCAB * EMB);
    k_prefix<<<dim3(BATCH, NCHUNK), 64, 0, stream>>>(emb, x, partial, A);
    k_gemm<<<dim3(M_TOTAL / 16 / 4, NCH), 256, 0, stream>>>(A, Wb, bias, C);
}